// Round 1
// baseline (718.929 us; speedup 1.0000x reference)
//
#include <hip/hip_runtime.h>
#include <hip/hip_bf16.h>
#include <stdint.h>

typedef unsigned int u32;
typedef unsigned short u16;
typedef __attribute__((ext_vector_type(4))) float f32x4;
typedef __attribute__((ext_vector_type(2))) float f32x2;
typedef __attribute__((ext_vector_type(8))) short bf16x8;
typedef __attribute__((ext_vector_type(4))) u16 u16x4;
typedef __attribute__((ext_vector_type(2))) u32 u32x2;

#define IN_DIM 4096
#define OUT_DIM 4096
#define M_DIM 8192

__device__ __forceinline__ u16 f2bf(float f) {
  u32 u = __builtin_bit_cast(u32, f);
  u += 0x7FFFu + ((u >> 16) & 1u);
  return (u16)(u >> 16);
}

// ---------------- input fake-quant ----------------

__global__ __launch_bounds__(256) void k_minmax(const float* __restrict__ x,
                                                float* __restrict__ pmin,
                                                float* __restrict__ pmax) {
  int col = blockIdx.x * 256 + threadIdx.x;
  const float* p = x + (size_t)blockIdx.y * 64 * IN_DIM + col;
  float mn = INFINITY, mx = -INFINITY;
#pragma unroll 8
  for (int r = 0; r < 64; ++r) {
    float v = p[(size_t)r * IN_DIM];
    mn = fminf(mn, v);
    mx = fmaxf(mx, v);
  }
  pmin[blockIdx.y * IN_DIM + col] = mn;
  pmax[blockIdx.y * IN_DIM + col] = mx;
}

__global__ __launch_bounds__(256) void k_scale(const float* __restrict__ pmin,
                                               const float* __restrict__ pmax,
                                               float* __restrict__ scl,
                                               float* __restrict__ zp) {
  int col = blockIdx.x * 256 + threadIdx.x;
  float mn = INFINITY, mx = -INFINITY;
  for (int r = 0; r < 128; ++r) {
    mn = fminf(mn, pmin[r * IN_DIM + col]);
    mx = fmaxf(mx, pmax[r * IN_DIM + col]);
  }
  float s = (mx - mn) / 255.0f;  // IEEE div, matches numpy f32
  if (!(s > 0.0f)) s = 1.0f;
  scl[col] = s;
  zp[col] = rintf(-mn / s);  // rintf = round-half-even = np.round
}

__global__ __launch_bounds__(256) void k_quant(const float* __restrict__ x,
                                               const float* __restrict__ scl,
                                               const float* __restrict__ zp,
                                               u16* __restrict__ xq) {
  int t = blockIdx.x * 256 + threadIdx.x;
#pragma unroll 2
  for (int it = 0; it < 16; ++it) {
    size_t i4 = (size_t)it * 524288 + t;  // 8388608 float4s total
    f32x4 xv = ((const f32x4*)x)[i4];
    int c4 = (int)(i4 & 1023);
    f32x4 sv = ((const f32x4*)scl)[c4];
    f32x4 zv = ((const f32x4*)zp)[c4];
    u16 o[4];
#pragma unroll
    for (int j = 0; j < 4; ++j) {
      float q = rintf(xv[j] / sv[j]) + zv[j];
      q = fminf(fmaxf(q, 0.0f), 255.0f);
      o[j] = f2bf((q - zv[j]) * sv[j]);
    }
    u32x2 ov;
    ov.x = (u32)o[0] | ((u32)o[1] << 16);
    ov.y = (u32)o[2] | ((u32)o[3] << 16);
    ((u32x2*)xq)[i4] = ov;
  }
}

// ---------------- weight decode + row FWHT (over IN) ----------------

__global__ __launch_bounds__(256) void k_decode_fwht(const int* __restrict__ trellis,
                                                     const float* __restrict__ lut,
                                                     const float* __restrict__ su,
                                                     const float* __restrict__ sv,
                                                     float* __restrict__ W1) {
  __shared__ float row[4096];
  __shared__ u16 words[512];
  int o = blockIdx.x;
  int t = threadIdx.x;
  const int* tr = trellis + (size_t)o * 512;
  words[t] = (u16)tr[t];
  words[t + 256] = (u16)tr[t + 256];
  float svo = sv[o];
  __syncthreads();
  int trl = t >> 4;        // local trellis row 0..15
  int s0 = (t & 15) * 8;   // 8 states per thread
  const u16* wp = words + trl * 32;
#pragma unroll
  for (int js = 0; js < 8; ++js) {
    int s = s0 + js;
    u32 hi = wp[s >> 2];
    u32 lo = wp[((s >> 2) + 1) & 31];
    int off = (s & 3) * 4;
    u32 st = ((hi << off) | (lo >> (16 - off))) & 0xFFFFu;
    f32x2 v = ((const f32x2*)lut)[st];
    int i = trl * 256 + s * 2;
    f32x2 suv = ((const f32x2*)su)[i >> 1];
    row[i] = v.x * suv.x * svo;
    row[i + 1] = v.y * suv.y * svo;
  }
  __syncthreads();
  // unnormalized FWHT over 4096, bit order 0..11 (same op order as reference)
  for (int lg = 0; lg < 12; ++lg) {
    int h = 1 << lg;
#pragma unroll
    for (int k = 0; k < 8; ++k) {
      int j = t + (k << 8);
      int idx = ((j >> lg) << (lg + 1)) | (j & (h - 1));
      float a = row[idx];
      float b = row[idx + h];
      row[idx] = a + b;
      row[idx + h] = a - b;
    }
    __syncthreads();
  }
  f32x4* dst = (f32x4*)(W1 + (size_t)o * 4096);
  const f32x4* srcv = (const f32x4*)row;
#pragma unroll
  for (int k = 0; k < 4; ++k) dst[t + (k << 8)] = srcv[t + (k << 8)];
}

// ---------------- column FWHT (over OUT), stage 1: bits 0..5 of row ----------------

__global__ __launch_bounds__(256) void k_col1(float* __restrict__ W1) {
  __shared__ float tile[64][68];
  int cb = blockIdx.x, rb = blockIdx.y;
  int t = threadIdx.x;
  int r = t >> 2;
  int c0 = (t & 3) << 4;
  float* base = W1 + (size_t)(rb * 64 + r) * 4096 + cb * 64 + c0;
#pragma unroll
  for (int k = 0; k < 4; ++k)
    *(f32x4*)&tile[r][c0 + k * 4] = *(const f32x4*)(base + k * 4);
  __syncthreads();
  int col = t & 63;
  int p0 = t >> 6;
  for (int lg = 0; lg < 6; ++lg) {
    int h = 1 << lg;
#pragma unroll
    for (int k = 0; k < 8; ++k) {
      int j = p0 + (k << 2);
      int idx = ((j >> lg) << (lg + 1)) | (j & (h - 1));
      float a = tile[idx][col];
      float b = tile[idx + h][col];
      tile[idx][col] = a + b;
      tile[idx + h][col] = a - b;
    }
    __syncthreads();
  }
#pragma unroll
  for (int k = 0; k < 4; ++k)
    *(f32x4*)(base + k * 4) = *(const f32x4*)&tile[r][c0 + k * 4];
}

// -------- column FWHT stage 2: bits 6..11 (rows strided by 64) + group scale + bf16 --------

__global__ __launch_bounds__(256) void k_col2(const float* __restrict__ W1,
                                              const float* __restrict__ gscale,
                                              u16* __restrict__ Wb) {
  __shared__ float tile[64][68];
  int cb = blockIdx.x, r0 = blockIdx.y;
  int t = threadIdx.x;
  int r1 = t >> 2;
  int c0 = (t & 3) << 4;
  const float* src = W1 + (size_t)(r1 * 64 + r0) * 4096 + cb * 64 + c0;
#pragma unroll
  for (int k = 0; k < 4; ++k)
    *(f32x4*)&tile[r1][c0 + k * 4] = *(const f32x4*)(src + k * 4);
  __syncthreads();
  int col = t & 63;
  int p0 = t >> 6;
  for (int lg = 0; lg < 6; ++lg) {
    int h = 1 << lg;
#pragma unroll
    for (int k = 0; k < 8; ++k) {
      int j = p0 + (k << 2);
      int idx = ((j >> lg) << (lg + 1)) | (j & (h - 1));
      float a = tile[idx][col];
      float b = tile[idx + h][col];
      tile[idx][col] = a + b;
      tile[idx + h][col] = a - b;
    }
    __syncthreads();
  }
  int o = r1 * 64 + r0;
  float gs = gscale[o * 16 + (cb >> 2)] * (1.0f / 4096.0f);
  u16* dst = Wb + (size_t)o * 4096 + cb * 64 + c0;
#pragma unroll
  for (int k = 0; k < 4; ++k) {
    f32x4 v = *(const f32x4*)&tile[r1][c0 + k * 4];
    u16x4 b;
    b[0] = f2bf(v[0] * gs);
    b[1] = f2bf(v[1] * gs);
    b[2] = f2bf(v[2] * gs);
    b[3] = f2bf(v[3] * gs);
    *(u16x4*)(dst + k * 4) = b;
  }
}

// ---------------- GEMM: C[8192][4096] = Xq[8192][4096] * Wb[4096][4096]^T ----------------
// m97-style: 128x128 tile, BK=64, 4 waves (2x2), global_load_lds width 16.

__global__ __launch_bounds__(256) void k_gemm(const u16* __restrict__ A,
                                              const u16* __restrict__ B,
                                              float* __restrict__ C) {
  __shared__ u16 As[128 * 64];
  __shared__ u16 Bs[128 * 64];
  constexpr int K = 4096, N = 4096;
  int t = threadIdx.x;
  int w = t >> 6, l = t & 63;
  int wr = w >> 1, wc = w & 1;
  int bm0 = blockIdx.y * 128, bn0 = blockIdx.x * 128;
  int lrow = l >> 3;
  int lcolb = (l & 7) << 4;  // byte col within 128B tile row
  const char* Ag = (const char*)A + ((size_t)(bm0 + w * 32 + lrow) * K) * 2 + lcolb;
  const char* Bg = (const char*)B + ((size_t)(bn0 + w * 32 + lrow) * K) * 2 + lcolb;
  char* AsL = (char*)As + (w << 12);
  char* BsL = (char*)Bs + (w << 12);
  f32x4 acc[4][4] = {};
  int arow = (wr << 6) | (l & 15);
  int brow = (wc << 6) | (l & 15);
  int kfrag = (l >> 4) << 3;  // 8 consecutive k elements per 16-lane group
  for (int k0 = 0; k0 < K; k0 += 64) {
    __syncthreads();
#pragma unroll
    for (int j = 0; j < 4; ++j) {
      __builtin_amdgcn_global_load_lds(
          (const __attribute__((address_space(1))) u32*)(Ag + (size_t)k0 * 2 + (size_t)j * 8 * K * 2),
          (__attribute__((address_space(3))) u32*)(AsL + j * 1024), 16, 0, 0);
      __builtin_amdgcn_global_load_lds(
          (const __attribute__((address_space(1))) u32*)(Bg + (size_t)k0 * 2 + (size_t)j * 8 * K * 2),
          (__attribute__((address_space(3))) u32*)(BsL + j * 1024), 16, 0, 0);
    }
    __syncthreads();
#pragma unroll
    for (int kk = 0; kk < 2; ++kk) {
      bf16x8 af[4], bfr[4];
#pragma unroll
      for (int m = 0; m < 4; ++m)
        af[m] = *(const bf16x8*)(As + ((arow + m * 16) << 6) + (kk << 5) + kfrag);
#pragma unroll
      for (int n = 0; n < 4; ++n)
        bfr[n] = *(const bf16x8*)(Bs + ((brow + n * 16) << 6) + (kk << 5) + kfrag);
#pragma unroll
      for (int m = 0; m < 4; ++m)
#pragma unroll
        for (int n = 0; n < 4; ++n)
          acc[m][n] = __builtin_amdgcn_mfma_f32_16x16x32_bf16(af[m], bfr[n], acc[m][n], 0, 0, 0);
    }
  }
  int cr = (l >> 4) << 2;
  int cc = l & 15;
#pragma unroll
  for (int m = 0; m < 4; ++m)
#pragma unroll
    for (int n = 0; n < 4; ++n) {
      float* cp = C + (size_t)(bm0 + wr * 64 + m * 16 + cr) * N + bn0 + wc * 64 + n * 16 + cc;
#pragma unroll
      for (int jj = 0; jj < 4; ++jj) cp[(size_t)jj * N] = acc[m][n][jj];
    }
}

// ---------------- launch ----------------

extern "C" void kernel_launch(void* const* d_in, const int* in_sizes, int n_in,
                              void* d_out, int out_size, void* d_ws, size_t ws_size,
                              hipStream_t stream) {
  const float* x = (const float*)d_in[0];
  const int* trellis = (const int*)d_in[1];
  const float* su = (const float*)d_in[2];
  const float* sv = (const float*)d_in[3];
  const float* wscale = (const float*)d_in[4];
  const float* lut = (const float*)d_in[5];
  float* out = (float*)d_out;

  char* ws = (char*)d_ws;
  float* W1 = (float*)ws;                          // 64 MiB (reused as xq after weights done)
  u16* Wb = (u16*)(ws + ((size_t)64 << 20));       // 32 MiB
  float* pmin = (float*)(ws + ((size_t)96 << 20)); // 2 MiB
  float* pmax = pmin + 128 * IN_DIM;               // 2 MiB
  float* scl = pmax + 128 * IN_DIM;
  float* zp = scl + IN_DIM;
  u16* xq = (u16*)W1;  // overlays W1 after k_col2 consumed it

  // weight chain first (so W1's space can be reused for xq)
  k_decode_fwht<<<dim3(OUT_DIM), 256, 0, stream>>>(trellis, lut, su, sv, W1);
  k_col1<<<dim3(64, 64), 256, 0, stream>>>(W1);
  k_col2<<<dim3(64, 64), 256, 0, stream>>>(W1, wscale, Wb);

  // input fake-quant chain (overwrites W1 with xq)
  k_minmax<<<dim3(16, 128), 256, 0, stream>>>(x, pmin, pmax);
  k_scale<<<dim3(16), 256, 0, stream>>>(pmin, pmax, scl, zp);
  k_quant<<<dim3(2048), 256, 0, stream>>>(x, scl, zp, xq);

  // GEMM
  k_gemm<<<dim3(32, 64), 256, 0, stream>>>(xq, Wb, out);
}

// Round 4
// 603.892 us; speedup vs baseline: 1.1905x; 1.1905x over previous
//
#include <hip/hip_runtime.h>
#include <hip/hip_bf16.h>
#include <stdint.h>

typedef unsigned int u32;
typedef unsigned short u16;
typedef __attribute__((ext_vector_type(4))) float f32x4;
typedef __attribute__((ext_vector_type(2))) float f32x2;
typedef __attribute__((ext_vector_type(8))) short bf16x8;
typedef __attribute__((ext_vector_type(4))) u16 u16x4;
typedef __attribute__((ext_vector_type(2))) u32 u32x2;

#define IN_DIM 4096
#define OUT_DIM 4096
#define M_DIM 8192

__device__ __forceinline__ u16 f2bf(float f) {
  u32 u = __builtin_bit_cast(u32, f);
  u += 0x7FFFu + ((u >> 16) & 1u);
  return (u16)(u >> 16);
}

// ---------------- input fake-quant ----------------

__global__ __launch_bounds__(256) void k_minmax(const float* __restrict__ x,
                                                float* __restrict__ pmin,
                                                float* __restrict__ pmax) {
  int col = blockIdx.x * 256 + threadIdx.x;
  const float* p = x + (size_t)blockIdx.y * 64 * IN_DIM + col;
  float mn = INFINITY, mx = -INFINITY;
#pragma unroll 8
  for (int r = 0; r < 64; ++r) {
    float v = p[(size_t)r * IN_DIM];
    mn = fminf(mn, v);
    mx = fmaxf(mx, v);
  }
  pmin[blockIdx.y * IN_DIM + col] = mn;
  pmax[blockIdx.y * IN_DIM + col] = mx;
}

__global__ __launch_bounds__(256) void k_scale(const float* __restrict__ pmin,
                                               const float* __restrict__ pmax,
                                               float* __restrict__ scl,
                                               float* __restrict__ zp) {
  int col = blockIdx.x * 256 + threadIdx.x;
  float mn = INFINITY, mx = -INFINITY;
  for (int r = 0; r < 128; ++r) {
    mn = fminf(mn, pmin[r * IN_DIM + col]);
    mx = fmaxf(mx, pmax[r * IN_DIM + col]);
  }
  float s = (mx - mn) / 255.0f;  // IEEE div, matches numpy f32
  if (!(s > 0.0f)) s = 1.0f;
  scl[col] = s;
  zp[col] = rintf(-mn / s);  // rintf = round-half-even = np.round
}

__global__ __launch_bounds__(256) void k_quant(const float* __restrict__ x,
                                               const float* __restrict__ scl,
                                               const float* __restrict__ zp,
                                               u16* __restrict__ xq) {
  int t = blockIdx.x * 256 + threadIdx.x;
#pragma unroll 2
  for (int it = 0; it < 16; ++it) {
    size_t i4 = (size_t)it * 524288 + t;  // 8388608 float4s total
    f32x4 xv = ((const f32x4*)x)[i4];
    int c4 = (int)(i4 & 1023);
    f32x4 sv = ((const f32x4*)scl)[c4];
    f32x4 zv = ((const f32x4*)zp)[c4];
    u16 o[4];
#pragma unroll
    for (int j = 0; j < 4; ++j) {
      float q = rintf(xv[j] / sv[j]) + zv[j];
      q = fminf(fmaxf(q, 0.0f), 255.0f);
      o[j] = f2bf((q - zv[j]) * sv[j]);
    }
    u32x2 ov;
    ov.x = (u32)o[0] | ((u32)o[1] << 16);
    ov.y = (u32)o[2] | ((u32)o[3] << 16);
    ((u32x2*)xq)[i4] = ov;
  }
}

// ---------------- weight decode + row FWHT (over IN) ----------------

__global__ __launch_bounds__(256) void k_decode_fwht(const int* __restrict__ trellis,
                                                     const float* __restrict__ lut,
                                                     const float* __restrict__ su,
                                                     const float* __restrict__ sv,
                                                     float* __restrict__ W1) {
  __shared__ float row[4096];
  __shared__ u16 words[512];
  int o = blockIdx.x;
  int t = threadIdx.x;
  const int* tr = trellis + (size_t)o * 512;
  words[t] = (u16)tr[t];
  words[t + 256] = (u16)tr[t + 256];
  float svo = sv[o];
  __syncthreads();
  int trl = t >> 4;        // local trellis row 0..15
  int s0 = (t & 15) * 8;   // 8 states per thread
  const u16* wp = words + trl * 32;
#pragma unroll
  for (int js = 0; js < 8; ++js) {
    int s = s0 + js;
    u32 hi = wp[s >> 2];
    u32 lo = wp[((s >> 2) + 1) & 31];
    int off = (s & 3) * 4;
    u32 st = ((hi << off) | (lo >> (16 - off))) & 0xFFFFu;
    f32x2 v = ((const f32x2*)lut)[st];
    int i = trl * 256 + s * 2;
    f32x2 suv = ((const f32x2*)su)[i >> 1];
    row[i] = v.x * suv.x * svo;
    row[i + 1] = v.y * suv.y * svo;
  }
  __syncthreads();
  // unnormalized FWHT over 4096, bit order 0..11 (same op order as reference)
  for (int lg = 0; lg < 12; ++lg) {
    int h = 1 << lg;
#pragma unroll
    for (int k = 0; k < 8; ++k) {
      int j = t + (k << 8);
      int idx = ((j >> lg) << (lg + 1)) | (j & (h - 1));
      float a = row[idx];
      float b = row[idx + h];
      row[idx] = a + b;
      row[idx + h] = a - b;
    }
    __syncthreads();
  }
  f32x4* dst = (f32x4*)(W1 + (size_t)o * 4096);
  const f32x4* srcv = (const f32x4*)row;
#pragma unroll
  for (int k = 0; k < 4; ++k) dst[t + (k << 8)] = srcv[t + (k << 8)];
}

// ---------------- column FWHT (over OUT), stage 1: bits 0..5 of row ----------------

__global__ __launch_bounds__(256) void k_col1(float* __restrict__ W1) {
  __shared__ float tile[64][68];
  int cb = blockIdx.x, rb = blockIdx.y;
  int t = threadIdx.x;
  int r = t >> 2;
  int c0 = (t & 3) << 4;
  float* base = W1 + (size_t)(rb * 64 + r) * 4096 + cb * 64 + c0;
#pragma unroll
  for (int k = 0; k < 4; ++k)
    *(f32x4*)&tile[r][c0 + k * 4] = *(const f32x4*)(base + k * 4);
  __syncthreads();
  int col = t & 63;
  int p0 = t >> 6;
  for (int lg = 0; lg < 6; ++lg) {
    int h = 1 << lg;
#pragma unroll
    for (int k = 0; k < 8; ++k) {
      int j = p0 + (k << 2);
      int idx = ((j >> lg) << (lg + 1)) | (j & (h - 1));
      float a = tile[idx][col];
      float b = tile[idx + h][col];
      tile[idx][col] = a + b;
      tile[idx + h][col] = a - b;
    }
    __syncthreads();
  }
#pragma unroll
  for (int k = 0; k < 4; ++k)
    *(f32x4*)(base + k * 4) = *(const f32x4*)&tile[r][c0 + k * 4];
}

// -------- column FWHT stage 2: bits 6..11 (rows strided by 64) + group scale + bf16 --------

__global__ __launch_bounds__(256) void k_col2(const float* __restrict__ W1,
                                              const float* __restrict__ gscale,
                                              u16* __restrict__ Wb) {
  __shared__ float tile[64][68];
  int cb = blockIdx.x, r0 = blockIdx.y;
  int t = threadIdx.x;
  int r1 = t >> 2;
  int c0 = (t & 3) << 4;
  const float* src = W1 + (size_t)(r1 * 64 + r0) * 4096 + cb * 64 + c0;
#pragma unroll
  for (int k = 0; k < 4; ++k)
    *(f32x4*)&tile[r1][c0 + k * 4] = *(const f32x4*)(src + k * 4);
  __syncthreads();
  int col = t & 63;
  int p0 = t >> 6;
  for (int lg = 0; lg < 6; ++lg) {
    int h = 1 << lg;
#pragma unroll
    for (int k = 0; k < 8; ++k) {
      int j = p0 + (k << 2);
      int idx = ((j >> lg) << (lg + 1)) | (j & (h - 1));
      float a = tile[idx][col];
      float b = tile[idx + h][col];
      tile[idx][col] = a + b;
      tile[idx + h][col] = a - b;
    }
    __syncthreads();
  }
  int o = r1 * 64 + r0;
  float gs = gscale[o * 16 + (cb >> 2)] * (1.0f / 4096.0f);
  u16* dst = Wb + (size_t)o * 4096 + cb * 64 + c0;
#pragma unroll
  for (int k = 0; k < 4; ++k) {
    f32x4 v = *(const f32x4*)&tile[r1][c0 + k * 4];
    u16x4 b;
    b[0] = f2bf(v[0] * gs);
    b[1] = f2bf(v[1] * gs);
    b[2] = f2bf(v[2] * gs);
    b[3] = f2bf(v[3] * gs);
    *(u16x4*)(dst + k * 4) = b;
  }
}

// ---------------- GEMM: C[8192][4096] = Xq[8192][4096] * Wb[4096][4096]^T ----------------
// 256x256 tile, BK=64 as two K-half planes [256 rows][32 k] (64B rows, swizzled),
// 8 waves (2M x 4N), per phase {ds_read frags, stage 1 plane, barrier, MFMA x16 under
// setprio}, counted vmcnt (never 0 in steady state).
//
// LDS plane layout: [buf][mat][kh][256][32] bf16; 16B slot s_phys = s_log ^ ((row>>1)&3).
// Staged with pre-swizzled GLOBAL source (global_load_lds writes linearly), read with
// the same involution -> conflict-free ds_read_b128 (2-way max, free per m136).
// Ring order per tile: [A.kh0, B.kh0, A.kh1, B.kh1]; consumption p0:{A0,B0} p1:{A1,B1}.
//
// vmcnt ledger (2 ops per STAGE), steady state tt in [0, NT-1):
//   enter p0: 4 outstanding {tt.q2, tt.q3}; p0 issues (tt+1).q0 -> 6;
//   end-p0 vmcnt(2) retires 4 oldest -> tt.q2, tt.q3 landed (read in p1/p3);
//   p1..p3 issue q1..q3 -> 8; end-p3 vmcnt(4) retires 4 -> (tt+1).q0,q1 landed.
// RACE FIX (round 4): final tile peeled. With no prefetch issued, vmcnt(2) at end-p0
// retired only 2 of 4 -> B.kh1 of the last tile could still be in flight when p1 read
// it (nondeterministic absmax 0.865 / replay divergence). Epilogue now drains vmcnt(0)
// at end-p0 of the peeled tile, per the template's "epilogue drains 4->2->0" rule.
// Prologue also drains vmcnt(0) (issue order of back-to-back STAGEs is not pinned).

#define GBAR __builtin_amdgcn_s_barrier()
#define MEMF asm volatile("" ::: "memory")
#define WLG asm volatile("s_waitcnt lgkmcnt(0)" ::: "memory")

#define STAGE(tt_, q_)                                                                   \
  do {                                                                                   \
    const char* g_ = ((q_)&1) ? Bg : Ag;                                                 \
    char* l_ = (char*)&lds[(tt_)&1][(q_)&1][(q_) >> 1][0] + sdst;                        \
    size_t go_ = (size_t)(tt_)*128 + ((q_) >> 1) * 64;                                   \
    __builtin_amdgcn_global_load_lds(                                                    \
        (const __attribute__((address_space(1))) u32*)(g_ + go_),                        \
        (__attribute__((address_space(3))) u32*)l_, 16, 0, 0);                           \
    __builtin_amdgcn_global_load_lds(                                                    \
        (const __attribute__((address_space(1))) u32*)(g_ + go_ + (size_t)16 * 4096 * 2),\
        (__attribute__((address_space(3))) u32*)(l_ + 1024), 16, 0, 0);                  \
  } while (0)

#define LDA(kh_, mh_)                                                                    \
  _Pragma("unroll") for (int m = 0; m < 4; ++m) a[m] = *(const bf16x8*)(                 \
      &lds[cur][0][kh_][(wr * 128 + (mh_)*64 + m * 16 + l15) * 32 + sphys]);

#define LDB(dst_, kh_)                                                                   \
  _Pragma("unroll") for (int n = 0; n < 4; ++n) dst_[n] = *(const bf16x8*)(              \
      &lds[cur][1][kh_][(wc * 64 + n * 16 + l15) * 32 + sphys]);

#define MM(bfrag_, mbase_)                                                               \
  _Pragma("unroll") for (int m = 0; m < 4; ++m)                                          \
  _Pragma("unroll") for (int n = 0; n < 4; ++n)                                          \
      acc[(mbase_) + m][n] = __builtin_amdgcn_mfma_f32_16x16x32_bf16(                    \
          a[m], bfrag_[n], acc[(mbase_) + m][n], 0, 0, 0);

__global__ __launch_bounds__(512, 2) void k_gemm(const u16* __restrict__ A,
                                                 const u16* __restrict__ B,
                                                 float* __restrict__ C) {
  __shared__ u16 lds[2][2][2][8192];  // 128 KiB
  constexpr int K = 4096, N = 4096, NT = 64;
  const int t = threadIdx.x;
  const int w = t >> 6, l = t & 63;
  const int wr = w >> 2, wc = w & 3;
  const int bm0 = blockIdx.y * 256, bn0 = blockIdx.x * 256;
  const int l15 = l & 15;
  // ds_read swizzled 16B-slot offset (u16 units): s_log = l>>4, xor = ((row>>1)&3) = (l>>1)&3
  const int sphys = (((l >> 4) ^ ((l >> 1) & 3)) << 3);

  // staging: wave w covers rows 32w..32w+31 of each plane (two 16-row units)
  const int srow = 32 * w + (l >> 2);
  const int scol = (((l & 3) ^ ((l >> 3) & 3)) << 4);  // pre-swizzled global 16B slot
  const char* Ag = (const char*)A + (size_t)(bm0 + srow) * (K * 2) + scol;
  const char* Bg = (const char*)B + (size_t)(bn0 + srow) * (K * 2) + scol;
  const int sdst = 32 * w * 64;  // wave-uniform LDS byte base within a plane

  f32x4 acc[8][4] = {};

  // prologue: stage all 4 planes of tile 0, full drain, publish.
  STAGE(0, 0);
  MEMF;
  STAGE(0, 1);
  MEMF;
  STAGE(0, 2);
  MEMF;
  STAGE(0, 3);
  MEMF;
  asm volatile("s_waitcnt vmcnt(0)" ::: "memory");
  GBAR;
  MEMF;

  for (int tt = 0; tt < NT - 1; ++tt) {
    const int cur = tt & 1;
    bf16x8 a[4], b0[4], b1[4];

    // ---- phase 0: (mh=0, kk=0) ----
    LDA(0, 0);
    LDB(b0, 0);
    STAGE(tt + 1, 0);
    MEMF;
    GBAR;
    WLG;
    __builtin_amdgcn_s_setprio(1);
    MM(b0, 0);
    __builtin_amdgcn_s_setprio(0);
    asm volatile("s_waitcnt vmcnt(2)" ::: "memory");  // ring tt.2, tt.3 landed
    MEMF;
    GBAR;
    MEMF;

    // ---- phase 1: (mh=0, kk=1) ----
    LDA(1, 0);
    LDB(b1, 1);
    STAGE(tt + 1, 1);
    MEMF;
    GBAR;
    WLG;
    __builtin_amdgcn_s_setprio(1);
    MM(b1, 0);
    __builtin_amdgcn_s_setprio(0);
    MEMF;
    GBAR;
    MEMF;

    // ---- phase 2: (mh=1, kk=0) ----
    LDA(0, 1);
    STAGE(tt + 1, 2);
    MEMF;
    GBAR;
    WLG;
    __builtin_amdgcn_s_setprio(1);
    MM(b0, 4);
    __builtin_amdgcn_s_setprio(0);
    MEMF;
    GBAR;
    MEMF;

    // ---- phase 3: (mh=1, kk=1) ----
    LDA(1, 1);
    STAGE(tt + 1, 3);
    MEMF;
    GBAR;
    WLG;
    __builtin_amdgcn_s_setprio(1);
    MM(b1, 4);
    __builtin_amdgcn_s_setprio(0);
    asm volatile("s_waitcnt vmcnt(4)" ::: "memory");  // ring (tt+1).0, (tt+1).1 landed
    MEMF;
    GBAR;
    MEMF;
  }

  // ---- peeled final tile (tt = NT-1): no prefetch, epilogue drain ----
  {
    const int cur = (NT - 1) & 1;
    bf16x8 a[4], b0[4], b1[4];

    // p0: q0/q1 landed via last loop iteration's vmcnt(4)+barrier
    LDA(0, 0);
    LDB(b0, 0);
    MEMF;
    GBAR;
    WLG;
    __builtin_amdgcn_s_setprio(1);
    MM(b0, 0);
    __builtin_amdgcn_s_setprio(0);
    asm volatile("s_waitcnt vmcnt(0)" ::: "memory");  // drain: q2,q3 landed
    MEMF;
    GBAR;
    MEMF;

    // p1..p3: LDS is read-only now; no barriers or vmem waits needed
    LDA(1, 0);
    LDB(b1, 1);
    WLG;
    __builtin_amdgcn_s_setprio(1);
    MM(b1, 0);
    __builtin_amdgcn_s_setprio(0);
    MEMF;

    LDA(0, 1);
    WLG;
    __builtin_amdgcn_s_setprio(1);
    MM(b0, 4);
    __builtin_amdgcn_s_setprio(0);
    MEMF;

    LDA(1, 1);
    WLG;
    __builtin_amdgcn_s_setprio(1);
    MM(b1, 4);
    __builtin_amdgcn_s_setprio(0);
    MEMF;
  }

  const int cr = (l >> 4) << 2;
#pragma unroll
  for (int m = 0; m < 8; ++m)
#pragma unroll
    for (int n = 0; n < 4; ++n) {
      float* cp = C + (size_t)(bm0 + wr * 128 + m * 16 + cr) * N + bn0 + wc * 64 + n * 16 + l15;
#pragma unroll
      for (int j = 0; j < 4; ++j) cp[(size_t)j * N] = acc[m][n][j];
    }
}

// ---------------- launch ----------------

extern "C" void kernel_launch(void* const* d_in, const int* in_sizes, int n_in,
                              void* d_out, int out_size, void* d_ws, size_t ws_size,
                              hipStream_t stream) {
  const float* x = (const float*)d_in[0];
  const int* trellis = (const int*)d_in[1];
  const float* su = (const float*)d_in[2];
  const float* sv = (const float*)d_in[3];
  const float* wscale = (const float*)d_in[4];
  const float* lut = (const float*)d_in[5];
  float* out = (float*)d_out;

  char* ws = (char*)d_ws;
  float* W1 = (float*)ws;                          // 64 MiB (reused as xq after weights done)
  u16* Wb = (u16*)(ws + ((size_t)64 << 20));       // 32 MiB
  float* pmin = (float*)(ws + ((size_t)96 << 20)); // 2 MiB
  float* pmax = pmin + 128 * IN_DIM;               // 2 MiB
  float* scl = pmax + 128 * IN_DIM;
  float* zp = scl + IN_DIM;
  u16* xq = (u16*)W1;  // overlays W1 after k_col2 consumed it

  // weight chain first (so W1's space can be reused for xq)
  k_decode_fwht<<<dim3(OUT_DIM), 256, 0, stream>>>(trellis, lut, su, sv, W1);
  k_col1<<<dim3(64, 64), 256, 0, stream>>>(W1);
  k_col2<<<dim3(64, 64), 256, 0, stream>>>(W1, wscale, Wb);

  // input fake-quant chain (overwrites W1 with xq)
  k_minmax<<<dim3(16, 128), 256, 0, stream>>>(x, pmin, pmax);
  k_scale<<<dim3(16), 256, 0, stream>>>(pmin, pmax, scl, zp);
  k_quant<<<dim3(2048), 256, 0, stream>>>(x, scl, zp, xq);

  // GEMM: grid (N/256, M/256), 512 threads
  k_gemm<<<dim3(16, 32), 512, 0, stream>>>(xq, Wb, out);
}

// Round 5
// 602.153 us; speedup vs baseline: 1.1939x; 1.0029x over previous
//
#include <hip/hip_runtime.h>
#include <hip/hip_bf16.h>
#include <stdint.h>

typedef unsigned int u32;
typedef unsigned short u16;
typedef __attribute__((ext_vector_type(4))) float f32x4;
typedef __attribute__((ext_vector_type(2))) float f32x2;
typedef __attribute__((ext_vector_type(8))) short bf16x8;
typedef __attribute__((ext_vector_type(4))) u16 u16x4;
typedef __attribute__((ext_vector_type(2))) u32 u32x2;

#define IN_DIM 4096
#define OUT_DIM 4096
#define M_DIM 8192

__device__ __forceinline__ u16 f2bf(float f) {
  u32 u = __builtin_bit_cast(u32, f);
  u += 0x7FFFu + ((u >> 16) & 1u);
  return (u16)(u >> 16);
}

// ---------------- input fake-quant ----------------
// f32x4-vectorized: thread owns 4 adjacent columns (one dwordx4 per row).

__global__ __launch_bounds__(256) void k_minmax(const float* __restrict__ x,
                                                float* __restrict__ pmin,
                                                float* __restrict__ pmax) {
  int c4 = blockIdx.x * 256 + threadIdx.x;  // f32x4 column 0..1023
  const f32x4* p = (const f32x4*)x + (size_t)blockIdx.y * 64 * 1024 + c4;
  f32x4 mn = {INFINITY, INFINITY, INFINITY, INFINITY};
  f32x4 mx = {-INFINITY, -INFINITY, -INFINITY, -INFINITY};
#pragma unroll 8
  for (int r = 0; r < 64; ++r) {
    f32x4 v = p[(size_t)r * 1024];
#pragma unroll
    for (int j = 0; j < 4; ++j) {
      mn[j] = fminf(mn[j], v[j]);
      mx[j] = fmaxf(mx[j], v[j]);
    }
  }
  ((f32x4*)pmin)[blockIdx.y * 1024 + c4] = mn;
  ((f32x4*)pmax)[blockIdx.y * 1024 + c4] = mx;
}

__global__ __launch_bounds__(256) void k_scale(const float* __restrict__ pmin,
                                               const float* __restrict__ pmax,
                                               float* __restrict__ scl,
                                               float* __restrict__ zp) {
  int c4 = blockIdx.x * 256 + threadIdx.x;  // f32x4 column 0..1023
  f32x4 mn = {INFINITY, INFINITY, INFINITY, INFINITY};
  f32x4 mx = {-INFINITY, -INFINITY, -INFINITY, -INFINITY};
  for (int r = 0; r < 128; ++r) {
    f32x4 a = ((const f32x4*)pmin)[r * 1024 + c4];
    f32x4 b = ((const f32x4*)pmax)[r * 1024 + c4];
#pragma unroll
    for (int j = 0; j < 4; ++j) {
      mn[j] = fminf(mn[j], a[j]);
      mx[j] = fmaxf(mx[j], b[j]);
    }
  }
  f32x4 sv, zv;
#pragma unroll
  for (int j = 0; j < 4; ++j) {
    float s = (mx[j] - mn[j]) / 255.0f;  // IEEE div, matches numpy f32
    if (!(s > 0.0f)) s = 1.0f;
    sv[j] = s;
    zv[j] = rintf(-mn[j] / s);  // round-half-even = np.round
  }
  ((f32x4*)scl)[c4] = sv;
  ((f32x4*)zp)[c4] = zv;
}

__global__ __launch_bounds__(256) void k_quant(const float* __restrict__ x,
                                               const float* __restrict__ scl,
                                               const float* __restrict__ zp,
                                               u16* __restrict__ xq) {
  int t = blockIdx.x * 256 + threadIdx.x;
#pragma unroll 2
  for (int it = 0; it < 16; ++it) {
    size_t i4 = (size_t)it * 524288 + t;  // 8388608 float4s total
    f32x4 xv = ((const f32x4*)x)[i4];
    int c4 = (int)(i4 & 1023);
    f32x4 sv = ((const f32x4*)scl)[c4];
    f32x4 zv = ((const f32x4*)zp)[c4];
    u16 o[4];
#pragma unroll
    for (int j = 0; j < 4; ++j) {
      float q = rintf(xv[j] / sv[j]) + zv[j];
      q = fminf(fmaxf(q, 0.0f), 255.0f);
      o[j] = f2bf((q - zv[j]) * sv[j]);
    }
    u32x2 ov;
    ov.x = (u32)o[0] | ((u32)o[1] << 16);
    ov.y = (u32)o[2] | ((u32)o[3] << 16);
    ((u32x2*)xq)[i4] = ov;
  }
}

// ---------------- weight decode + row FWHT (over IN) ----------------
// Radix-4^2 restructure: decode yields 16 CONSECUTIVE elements per thread ->
// stages 0-3 in-register; then 4 LDS passes, each 2 stages on 4 f32x4 vectors
// (4x ds_read_b128 + butterflies + 4x ds_write_b128). Slot swizzle
// phys = u ^ ((u>>3)&7) achieves the 8-lane/bank-quad floor for every pass's
// access pattern (derivation in session notes). Within a pass each slot is
// read+written by exactly one thread -> barrier only BETWEEN passes.
// FP note: stage-order regrouping reassociates identically-paired adds only;
// value-level tree per butterfly unchanged, rounding differences ~1e-5 rel,
// absmax margin is 3.5x.

__global__ __launch_bounds__(256) void k_decode_fwht(const int* __restrict__ trellis,
                                                     const float* __restrict__ lut,
                                                     const float* __restrict__ su,
                                                     const float* __restrict__ sv,
                                                     float* __restrict__ W1) {
  __shared__ f32x4 ldsv[1024];  // 16 KiB, swizzled slots
  __shared__ u16 words[512];
  int o = blockIdx.x;
  int t = threadIdx.x;
  const int* tr = trellis + (size_t)o * 512;
  words[t] = (u16)tr[t];
  words[t + 256] = (u16)tr[t + 256];
  float svo = sv[o];
  __syncthreads();
  int trl = t >> 4;        // trellis row 0..15
  int s0 = (t & 15) * 8;   // 8 states -> 16 consecutive elements
  int base = trl * 256 + (t & 15) * 16;
  const u16* wp = words + trl * 32;
  float v[16];
#pragma unroll
  for (int js = 0; js < 8; ++js) {
    int s = s0 + js;
    u32 hi = wp[s >> 2];
    u32 lo = wp[((s >> 2) + 1) & 31];
    int off = (s & 3) * 4;
    u32 st = ((hi << off) | (lo >> (16 - off))) & 0xFFFFu;
    f32x2 lv = ((const f32x2*)lut)[st];
    f32x2 suv = ((const f32x2*)su)[(base >> 1) + js];
    v[2 * js] = lv.x * suv.x * svo;
    v[2 * js + 1] = lv.y * suv.y * svo;
  }
  // stages 0..3 in-register (same butterfly pairing as reference)
#pragma unroll
  for (int lg = 0; lg < 4; ++lg) {
    int h = 1 << lg;
#pragma unroll
    for (int i = 0; i < 8; ++i) {
      int idx = ((i >> lg) << (lg + 1)) | (i & (h - 1));
      float a = v[idx], b = v[idx + h];
      v[idx] = a + b;
      v[idx + h] = a - b;
    }
  }
  // write 4 vectors to swizzled LDS
  int ub = base >> 2;
#pragma unroll
  for (int k = 0; k < 4; ++k) {
    int u = ub + k;
    ldsv[u ^ ((u >> 3) & 7)] = *(f32x4*)&v[4 * k];
  }
  __syncthreads();
  // passes p=1..4: stages (2p+2, 2p+3) on vectors {u0 + k*hv}, hv = 4^p
#pragma unroll
  for (int p = 1; p <= 4; ++p) {
    const int hv = 1 << (2 * p);
    int u0 = (t / hv) * 4 * hv + (t % hv);
    f32x4 y0, y1, y2, y3;
    {
      int u = u0;
      y0 = ldsv[u ^ ((u >> 3) & 7)];
      u = u0 + hv;
      y1 = ldsv[u ^ ((u >> 3) & 7)];
      u = u0 + 2 * hv;
      y2 = ldsv[u ^ ((u >> 3) & 7)];
      u = u0 + 3 * hv;
      y3 = ldsv[u ^ ((u >> 3) & 7)];
    }
    f32x4 a0 = y0 + y1, a1 = y0 - y1;
    f32x4 a2 = y2 + y3, a3 = y2 - y3;
    y0 = a0 + a2;
    y2 = a0 - a2;
    y1 = a1 + a3;
    y3 = a1 - a3;
    if (p == 4) {
      // u0 == t; vectors t + 256k -> fully coalesced global f32x4 stores
      f32x4* dst = (f32x4*)(W1 + (size_t)o * 4096);
      dst[t] = y0;
      dst[t + 256] = y1;
      dst[t + 512] = y2;
      dst[t + 768] = y3;
    } else {
      int u = u0;
      ldsv[u ^ ((u >> 3) & 7)] = y0;
      u = u0 + hv;
      ldsv[u ^ ((u >> 3) & 7)] = y1;
      u = u0 + 2 * hv;
      ldsv[u ^ ((u >> 3) & 7)] = y2;
      u = u0 + 3 * hv;
      ldsv[u ^ ((u >> 3) & 7)] = y3;
      __syncthreads();
    }
  }
}

// ---------------- column FWHT (over OUT), stage 1: bits 0..5 of row ----------------

__global__ __launch_bounds__(256) void k_col1(float* __restrict__ W1) {
  __shared__ float tile[64][68];
  int cb = blockIdx.x, rb = blockIdx.y;
  int t = threadIdx.x;
  int r = t >> 2;
  int c0 = (t & 3) << 4;
  float* base = W1 + (size_t)(rb * 64 + r) * 4096 + cb * 64 + c0;
#pragma unroll
  for (int k = 0; k < 4; ++k)
    *(f32x4*)&tile[r][c0 + k * 4] = *(const f32x4*)(base + k * 4);
  __syncthreads();
  int col = t & 63;
  int p0 = t >> 6;
  for (int lg = 0; lg < 6; ++lg) {
    int h = 1 << lg;
#pragma unroll
    for (int k = 0; k < 8; ++k) {
      int j = p0 + (k << 2);
      int idx = ((j >> lg) << (lg + 1)) | (j & (h - 1));
      float a = tile[idx][col];
      float b = tile[idx + h][col];
      tile[idx][col] = a + b;
      tile[idx + h][col] = a - b;
    }
    __syncthreads();
  }
#pragma unroll
  for (int k = 0; k < 4; ++k)
    *(f32x4*)(base + k * 4) = *(const f32x4*)&tile[r][c0 + k * 4];
}

// -------- column FWHT stage 2: bits 6..11 (rows strided by 64) + group scale + bf16 --------

__global__ __launch_bounds__(256) void k_col2(const float* __restrict__ W1,
                                              const float* __restrict__ gscale,
                                              u16* __restrict__ Wb) {
  __shared__ float tile[64][68];
  int cb = blockIdx.x, r0 = blockIdx.y;
  int t = threadIdx.x;
  int r1 = t >> 2;
  int c0 = (t & 3) << 4;
  const float* src = W1 + (size_t)(r1 * 64 + r0) * 4096 + cb * 64 + c0;
#pragma unroll
  for (int k = 0; k < 4; ++k)
    *(f32x4*)&tile[r1][c0 + k * 4] = *(const f32x4*)(src + k * 4);
  __syncthreads();
  int col = t & 63;
  int p0 = t >> 6;
  for (int lg = 0; lg < 6; ++lg) {
    int h = 1 << lg;
#pragma unroll
    for (int k = 0; k < 8; ++k) {
      int j = p0 + (k << 2);
      int idx = ((j >> lg) << (lg + 1)) | (j & (h - 1));
      float a = tile[idx][col];
      float b = tile[idx + h][col];
      tile[idx][col] = a + b;
      tile[idx + h][col] = a - b;
    }
    __syncthreads();
  }
  int o = r1 * 64 + r0;
  float gs = gscale[o * 16 + (cb >> 2)] * (1.0f / 4096.0f);
  u16* dst = Wb + (size_t)o * 4096 + cb * 64 + c0;
#pragma unroll
  for (int k = 0; k < 4; ++k) {
    f32x4 v = *(const f32x4*)&tile[r1][c0 + k * 4];
    u16x4 b;
    b[0] = f2bf(v[0] * gs);
    b[1] = f2bf(v[1] * gs);
    b[2] = f2bf(v[2] * gs);
    b[3] = f2bf(v[3] * gs);
    *(u16x4*)(dst + k * 4) = b;
  }
}

// ---------------- GEMM: C[8192][4096] = Xq[8192][4096] * Wb[4096][4096]^T ----------------
// 256x256 tile, BK=64 as two K-half planes [256 rows][32 k] (64B rows, swizzled),
// 8 waves (2M x 4N), per phase {ds_read frags, stage 1 plane, barrier, MFMA x16 under
// setprio}, counted vmcnt (never 0 in steady state). Sync schedule VERIFIED (round 4) —
// FROZEN. Round 5 adds only the XCD-aware block swizzle (work remap, T1): nwg=512,
// 512%8==0 -> nid=(bid&7)*64+(bid>>3); each XCD owns 4 consecutive A row-panels
// (2MB each, L2-resident, reused 16x).
//
// vmcnt ledger (2 ops per STAGE), steady state tt in [0, NT-1):
//   enter p0: 4 outstanding {tt.q2, tt.q3}; p0 issues (tt+1).q0 -> 6;
//   end-p0 vmcnt(2) retires 4 oldest -> tt.q2, tt.q3 landed (read in p1/p3);
//   p1..p3 issue q1..q3 -> 8; end-p3 vmcnt(4) retires 4 -> (tt+1).q0,q1 landed.
// Final tile peeled with vmcnt(0) drain at end-p0 (epilogue drains 4->2->0).
// Prologue drains vmcnt(0) (issue order of back-to-back STAGEs is not pinned).

#define GBAR __builtin_amdgcn_s_barrier()
#define MEMF asm volatile("" ::: "memory")
#define WLG asm volatile("s_waitcnt lgkmcnt(0)" ::: "memory")

#define STAGE(tt_, q_)                                                                   \
  do {                                                                                   \
    const char* g_ = ((q_)&1) ? Bg : Ag;                                                 \
    char* l_ = (char*)&lds[(tt_)&1][(q_)&1][(q_) >> 1][0] + sdst;                        \
    size_t go_ = (size_t)(tt_)*128 + ((q_) >> 1) * 64;                                   \
    __builtin_amdgcn_global_load_lds(                                                    \
        (const __attribute__((address_space(1))) u32*)(g_ + go_),                        \
        (__attribute__((address_space(3))) u32*)l_, 16, 0, 0);                           \
    __builtin_amdgcn_global_load_lds(                                                    \
        (const __attribute__((address_space(1))) u32*)(g_ + go_ + (size_t)16 * 4096 * 2),\
        (__attribute__((address_space(3))) u32*)(l_ + 1024), 16, 0, 0);                  \
  } while (0)

#define LDA(kh_, mh_)                                                                    \
  _Pragma("unroll") for (int m = 0; m < 4; ++m) a[m] = *(const bf16x8*)(                 \
      &lds[cur][0][kh_][(wr * 128 + (mh_)*64 + m * 16 + l15) * 32 + sphys]);

#define LDB(dst_, kh_)                                                                   \
  _Pragma("unroll") for (int n = 0; n < 4; ++n) dst_[n] = *(const bf16x8*)(              \
      &lds[cur][1][kh_][(wc * 64 + n * 16 + l15) * 32 + sphys]);

#define MM(bfrag_, mbase_)                                                               \
  _Pragma("unroll") for (int m = 0; m < 4; ++m)                                          \
  _Pragma("unroll") for (int n = 0; n < 4; ++n)                                          \
      acc[(mbase_) + m][n] = __builtin_amdgcn_mfma_f32_16x16x32_bf16(                    \
          a[m], bfrag_[n], acc[(mbase_) + m][n], 0, 0, 0);

__global__ __launch_bounds__(512, 2) void k_gemm(const u16* __restrict__ A,
                                                 const u16* __restrict__ B,
                                                 float* __restrict__ C) {
  __shared__ u16 lds[2][2][2][8192];  // 128 KiB
  constexpr int K = 4096, N = 4096, NT = 64;
  const int t = threadIdx.x;
  const int w = t >> 6, l = t & 63;
  const int wr = w >> 2, wc = w & 3;
  // XCD-aware bijective swizzle (nwg = 512 = 8*64)
  const int bid = blockIdx.y * 16 + blockIdx.x;
  const int nid = (bid & 7) * 64 + (bid >> 3);
  const int bm0 = (nid >> 4) * 256, bn0 = (nid & 15) * 256;
  const int l15 = l & 15;
  // ds_read swizzled 16B-slot offset (u16 units): s_log = l>>4, xor = ((row>>1)&3) = (l>>1)&3
  const int sphys = (((l >> 4) ^ ((l >> 1) & 3)) << 3);

  // staging: wave w covers rows 32w..32w+31 of each plane (two 16-row units)
  const int srow = 32 * w + (l >> 2);
  const int scol = (((l & 3) ^ ((l >> 3) & 3)) << 4);  // pre-swizzled global 16B slot
  const char* Ag = (const char*)A + (size_t)(bm0 + srow) * (K * 2) + scol;
  const char* Bg = (const char*)B + (size_t)(bn0 + srow) * (K * 2) + scol;
  const int sdst = 32 * w * 64;  // wave-uniform LDS byte base within a plane

  f32x4 acc[8][4] = {};

  // prologue: stage all 4 planes of tile 0, full drain, publish.
  STAGE(0, 0);
  MEMF;
  STAGE(0, 1);
  MEMF;
  STAGE(0, 2);
  MEMF;
  STAGE(0, 3);
  MEMF;
  asm volatile("s_waitcnt vmcnt(0)" ::: "memory");
  GBAR;
  MEMF;

  for (int tt = 0; tt < NT - 1; ++tt) {
    const int cur = tt & 1;
    bf16x8 a[4], b0[4], b1[4];

    // ---- phase 0: (mh=0, kk=0) ----
    LDA(0, 0);
    LDB(b0, 0);
    STAGE(tt + 1, 0);
    MEMF;
    GBAR;
    WLG;
    __builtin_amdgcn_s_setprio(1);
    MM(b0, 0);
    __builtin_amdgcn_s_setprio(0);
    asm volatile("s_waitcnt vmcnt(2)" ::: "memory");  // ring tt.2, tt.3 landed
    MEMF;
    GBAR;
    MEMF;

    // ---- phase 1: (mh=0, kk=1) ----
    LDA(1, 0);
    LDB(b1, 1);
    STAGE(tt + 1, 1);
    MEMF;
    GBAR;
    WLG;
    __builtin_amdgcn_s_setprio(1);
    MM(b1, 0);
    __builtin_amdgcn_s_setprio(0);
    MEMF;
    GBAR;
    MEMF;

    // ---- phase 2: (mh=1, kk=0) ----
    LDA(0, 1);
    STAGE(tt + 1, 2);
    MEMF;
    GBAR;
    WLG;
    __builtin_amdgcn_s_setprio(1);
    MM(b0, 4);
    __builtin_amdgcn_s_setprio(0);
    MEMF;
    GBAR;
    MEMF;

    // ---- phase 3: (mh=1, kk=1) ----
    LDA(1, 1);
    STAGE(tt + 1, 3);
    MEMF;
    GBAR;
    WLG;
    __builtin_amdgcn_s_setprio(1);
    MM(b1, 4);
    __builtin_amdgcn_s_setprio(0);
    asm volatile("s_waitcnt vmcnt(4)" ::: "memory");  // ring (tt+1).0, (tt+1).1 landed
    MEMF;
    GBAR;
    MEMF;
  }

  // ---- peeled final tile (tt = NT-1): no prefetch, epilogue drain ----
  {
    const int cur = (NT - 1) & 1;
    bf16x8 a[4], b0[4], b1[4];

    // p0: q0/q1 landed via last loop iteration's vmcnt(4)+barrier
    LDA(0, 0);
    LDB(b0, 0);
    MEMF;
    GBAR;
    WLG;
    __builtin_amdgcn_s_setprio(1);
    MM(b0, 0);
    __builtin_amdgcn_s_setprio(0);
    asm volatile("s_waitcnt vmcnt(0)" ::: "memory");  // drain: q2,q3 landed
    MEMF;
    GBAR;
    MEMF;

    // p1..p3: LDS is read-only now; no barriers or vmem waits needed
    LDA(1, 0);
    LDB(b1, 1);
    WLG;
    __builtin_amdgcn_s_setprio(1);
    MM(b1, 0);
    __builtin_amdgcn_s_setprio(0);
    MEMF;

    LDA(0, 1);
    WLG;
    __builtin_amdgcn_s_setprio(1);
    MM(b0, 4);
    __builtin_amdgcn_s_setprio(0);
    MEMF;

    LDA(1, 1);
    WLG;
    __builtin_amdgcn_s_setprio(1);
    MM(b1, 4);
    __builtin_amdgcn_s_setprio(0);
    MEMF;
  }

  const int cr = (l >> 4) << 2;
#pragma unroll
  for (int m = 0; m < 8; ++m)
#pragma unroll
    for (int n = 0; n < 4; ++n) {
      float* cp = C + (size_t)(bm0 + wr * 128 + m * 16 + cr) * N + bn0 + wc * 64 + n * 16 + l15;
#pragma unroll
      for (int j = 0; j < 4; ++j) cp[(size_t)j * N] = acc[m][n][j];
    }
}

// ---------------- launch ----------------

extern "C" void kernel_launch(void* const* d_in, const int* in_sizes, int n_in,
                              void* d_out, int out_size, void* d_ws, size_t ws_size,
                              hipStream_t stream) {
  const float* x = (const float*)d_in[0];
  const int* trellis = (const int*)d_in[1];
  const float* su = (const float*)d_in[2];
  const float* sv = (const float*)d_in[3];
  const float* wscale = (const float*)d_in[4];
  const float* lut = (const float*)d_in[5];
  float* out = (float*)d_out;

  char* ws = (char*)d_ws;
  float* W1 = (float*)ws;                          // 64 MiB (reused as xq after weights done)
  u16* Wb = (u16*)(ws + ((size_t)64 << 20));       // 32 MiB
  float* pmin = (float*)(ws + ((size_t)96 << 20)); // 2 MiB
  float* pmax = pmin + 128 * IN_DIM;               // 2 MiB
  float* scl = pmax + 128 * IN_DIM;
  float* zp = scl + IN_DIM;
  u16* xq = (u16*)W1;  // overlays W1 after k_col2 consumed it

  // weight chain first (so W1's space can be reused for xq)
  k_decode_fwht<<<dim3(OUT_DIM), 256, 0, stream>>>(trellis, lut, su, sv, W1);
  k_col1<<<dim3(64, 64), 256, 0, stream>>>(W1);
  k_col2<<<dim3(64, 64), 256, 0, stream>>>(W1, wscale, Wb);

  // input fake-quant chain (overwrites W1 with xq)
  k_minmax<<<dim3(4, 128), 256, 0, stream>>>(x, pmin, pmax);
  k_scale<<<dim3(4), 256, 0, stream>>>(pmin, pmax, scl, zp);
  k_quant<<<dim3(2048), 256, 0, stream>>>(x, scl, zp, xq);

  // GEMM: grid (N/256, M/256), 512 threads
  k_gemm<<<dim3(16, 32), 512, 0, stream>>>(xq, Wb, out);
}